// Round 7
// baseline (484.635 us; speedup 1.0000x reference)
//
#include <hip/hip_runtime.h>

typedef __attribute__((ext_vector_type(8))) short short8;
typedef __attribute__((ext_vector_type(4))) float floatx4;

constexpr int DIM   = 128;   // dim_in == dim_out
constexpr int NB    = 4;     // bases
constexpr int NR    = 8;     // relations
constexpr int BROWS = 512;   // rows per sort bucket
constexpr int BCAP  = 16384; // fixed bucket capacity (mean 8192, +90 sigma)

static __device__ __forceinline__ unsigned short f2bf(float f) {
    unsigned int u = __float_as_uint(f);
    u += 0x7FFFu + ((u >> 16) & 1u);
    return (unsigned short)(u >> 16);
}
static __device__ __forceinline__ float bf_lo(unsigned int h) {
    return __uint_as_float(h << 16);
}
static __device__ __forceinline__ float bf_hi(unsigned int h) {
    return __uint_as_float(h & 0xFFFF0000u);
}

// ---------------------------------------------------------------------------
// Vfrag[b][ot][ks][lane][j] = V[b][k][o], k=ks*32+(lane>>4)*8+j, o=ot*16+(lane&15)
// ---------------------------------------------------------------------------
__global__ __launch_bounds__(256) void build_vfrag(
    const float* __restrict__ V, unsigned short* __restrict__ VfragG)
{
    int idx  = blockIdx.x * 256 + threadIdx.x;   // 0 .. 8191
    int lane = idx & 63;
    int ks   = (idx >> 6) & 3;
    int ot   = (idx >> 8) & 7;
    int b    = idx >> 11;

    int o  = ot * 16 + (lane & 15);
    int kb = ks * 32 + (lane >> 4) * 8;

    short8 v;
#pragma unroll
    for (int j = 0; j < 8; ++j)
        v[j] = (short)f2bf(V[((size_t)b * DIM + kb + j) * DIM + o]);
    *reinterpret_cast<short8*>(VfragG + (size_t)idx * 8) = v;
}

// ---------------------------------------------------------------------------
// W_r fragments (fallback path only)
// ---------------------------------------------------------------------------
__global__ __launch_bounds__(256) void build_wfrag(
    const float* __restrict__ A, const float* __restrict__ V,
    unsigned short* __restrict__ Wfrag)
{
    int idx  = blockIdx.x * 256 + threadIdx.x;   // 0 .. 16383
    int lane = idx & 63;
    int ks   = (idx >> 6) & 3;
    int ot   = (idx >> 8) & 7;
    int r    = idx >> 11;

    int o     = ot * 16 + (lane & 15);
    int kbase = ks * 32 + (lane >> 4) * 8;

    float a0 = A[r * NB + 0], a1 = A[r * NB + 1];
    float a2 = A[r * NB + 2], a3 = A[r * NB + 3];

    short8 v;
#pragma unroll
    for (int j = 0; j < 8; ++j) {
        int k = kbase + j;
        float w = a0 * V[(0 * DIM + k) * DIM + o]
                + a1 * V[(1 * DIM + k) * DIM + o]
                + a2 * V[(2 * DIM + k) * DIM + o]
                + a3 * V[(3 * DIM + k) * DIM + o];
        v[j] = (short)f2bf(w);
    }
    *reinterpret_cast<short8*>(Wfrag + (size_t)idx * 8) = v;
}

// ---------------------------------------------------------------------------
// H (fp32) -> Hbf (bf16), row-major [Ne][128]
// ---------------------------------------------------------------------------
__global__ __launch_bounds__(256) void h_to_bf(
    const float* __restrict__ H, unsigned short* __restrict__ Hbf, int n8)
{
    int i = blockIdx.x * 256 + threadIdx.x;
    if (i >= n8) return;
    const float4* hp = reinterpret_cast<const float4*>(H) + (size_t)i * 2;
    float4 f0 = hp[0];
    float4 f1 = hp[1];
    short8 v;
    v[0] = (short)f2bf(f0.x); v[1] = (short)f2bf(f0.y);
    v[2] = (short)f2bf(f0.z); v[3] = (short)f2bf(f0.w);
    v[4] = (short)f2bf(f1.x); v[5] = (short)f2bf(f1.y);
    v[6] = (short)f2bf(f1.z); v[7] = (short)f2bf(f1.w);
    *reinterpret_cast<short8*>(Hbf + (size_t)i * 8) = v;
}

// ---------------------------------------------------------------------------
// Sort pass 1: scatter edges into fixed-capacity coarse buckets
// (bucket = row >> 9). Per-block LDS histogram -> one global atomicAdd per
// (block,bucket) -> contiguous runs. No rowStart dependency.
// Record: key = localRow<<20 | r<<17 | col  (9 | 3 | 17 bits), val fp32.
// ---------------------------------------------------------------------------
__global__ __launch_bounds__(256) void bucket_scatter(
    const int* __restrict__ erow, const int* __restrict__ ecol,
    const float* __restrict__ eval, int* __restrict__ bcnt,
    int2* __restrict__ sorted1, int n, int E, int chunk)
{
    __shared__ int cnt[256];
    __shared__ int base[256];
    int t = threadIdx.x;
    cnt[t] = 0;
    __syncthreads();

    int s = blockIdx.x * chunk;
    int e = s + chunk; if (e > n) e = n;

    for (int i = s + t; i < e; i += 256)
        atomicAdd(&cnt[erow[i] >> 9], 1);
    __syncthreads();

    int c = cnt[t];
    base[t] = (c > 0) ? atomicAdd(&bcnt[t], c) : 0;
    cnt[t] = 0;
    __syncthreads();

    for (int i = s + t; i < e; i += 256) {
        int row = erow[i];
        int bkt = row >> 9;
        int rank = atomicAdd(&cnt[bkt], 1);
        int r = (int)((unsigned)i / (unsigned)E);
        int2 m;
        m.x = ((row & (BROWS - 1)) << 20) | (r << 17) | ecol[i];
        m.y = __float_as_int(eval[i]);
        sorted1[(size_t)bkt * BCAP + base[bkt] + rank] = m;
    }
}

// ---------------------------------------------------------------------------
// Exclusive scan over the 196 bucket counts (single block); also finalize
// rowStart[Ne] = total edge count.
// ---------------------------------------------------------------------------
__global__ __launch_bounds__(256) void bucket_scan(
    const int* __restrict__ bcnt, int* __restrict__ bstart,
    int* __restrict__ rowStart, int nbuc, int Ne)
{
    __shared__ int sd[256];
    int t = threadIdx.x;
    int c = (t < nbuc) ? bcnt[t] : 0;
    sd[t] = c; __syncthreads();
#pragma unroll
    for (int off = 1; off < 256; off <<= 1) {
        int v = (t >= off) ? sd[t - off] : 0;
        __syncthreads();
        sd[t] += v;
        __syncthreads();
    }
    if (t < nbuc) bstart[t] = sd[t] - c;
    if (t == nbuc - 1) rowStart[Ne] = sd[t];
}

// ---------------------------------------------------------------------------
// Sort pass 2: one block per bucket. Contiguous read of the bucket's
// records; per-row LDS histogram + scan -> emits rowStart for its 512 rows
// and compacts records to exact final positions (writes land in the
// bucket's ~128KB output window -> L2-absorbed).
// ---------------------------------------------------------------------------
__global__ __launch_bounds__(256) void bucket_sort(
    const int2* __restrict__ sorted1, const int* __restrict__ bcnt,
    const int* __restrict__ bstart, int* __restrict__ rowStart,
    int2* __restrict__ sorted, int Ne)
{
    __shared__ int hcnt[BROWS];
    __shared__ int hoff[BROWS];
    int b = blockIdx.x;
    int t = threadIdx.x;
    hcnt[t] = 0; hcnt[t + 256] = 0;
    __syncthreads();

    int n = bcnt[b];
    const int2* src = sorted1 + (size_t)b * BCAP;

    for (int i = t; i < n; i += 256)
        atomicAdd(&hcnt[(unsigned)src[i].x >> 20], 1);
    __syncthreads();

    if (t == 0) {
        int run = 0;
#pragma unroll 8
        for (int j = 0; j < BROWS; ++j) { hoff[j] = run; run += hcnt[j]; }
    }
    __syncthreads();

    int bs = bstart[b];
    int rs = b * BROWS;
    int nr = Ne - rs; if (nr > BROWS) nr = BROWS;
    for (int j = t; j < nr; j += 256)
        rowStart[rs + j] = bs + hoff[j];

    hcnt[t] = 0; hcnt[t + 256] = 0;
    __syncthreads();

    for (int i = t; i < n; i += 256) {
        int2 m = src[i];
        int lr = (unsigned)m.x >> 20;
        int pos = bs + hoff[lr] + atomicAdd(&hcnt[lr], 1);
        sorted[pos] = m;
    }
}

// ---------------------------------------------------------------------------
// K_A: basis aggregation. One wave per destination row.
// Agg[row][b*128 + i] = sum_{edges->row} val*A[r,b]*Hbf[col][i]   (bf16 out)
// Per-edge control (record decode, A[r] fetch, gather base) is scalarized
// via readfirstlane -> s_load + SGPR-base gathers; VALU does only the FMAs.
// ---------------------------------------------------------------------------
__global__ __launch_bounds__(256) void agg_kernel(
    const unsigned short* __restrict__ Hbf,
    const int*  __restrict__ rowStart,
    const int2* __restrict__ sorted,
    const float* __restrict__ Aw,
    unsigned short* __restrict__ Agg, int Ne)
{
    int tid  = threadIdx.x;
    int wid  = __builtin_amdgcn_readfirstlane(blockIdx.x * 4 + (tid >> 6));
    if (wid >= Ne) return;
    int lane = tid & 63;

    int s = __builtin_amdgcn_readfirstlane(rowStart[wid]);
    int e = __builtin_amdgcn_readfirstlane(rowStart[wid + 1]);

    const float4* Af = reinterpret_cast<const float4*>(Aw);

    float2 acc[4];
#pragma unroll
    for (int b = 0; b < 4; ++b) { acc[b].x = 0.f; acc[b].y = 0.f; }

    int i = s;
    for (; i + 4 <= e; i += 4) {
        int2 m0 = sorted[i],     m1 = sorted[i + 1];
        int2 m2 = sorted[i + 2], m3 = sorted[i + 3];
        int k0 = __builtin_amdgcn_readfirstlane(m0.x);
        int k1 = __builtin_amdgcn_readfirstlane(m1.x);
        int k2 = __builtin_amdgcn_readfirstlane(m2.x);
        int k3 = __builtin_amdgcn_readfirstlane(m3.x);
        float v0 = __uint_as_float(__builtin_amdgcn_readfirstlane(m0.y));
        float v1 = __uint_as_float(__builtin_amdgcn_readfirstlane(m1.y));
        float v2 = __uint_as_float(__builtin_amdgcn_readfirstlane(m2.y));
        float v3 = __uint_as_float(__builtin_amdgcn_readfirstlane(m3.y));

        unsigned int h0 = reinterpret_cast<const unsigned int*>(
            Hbf + (size_t)(k0 & 0x1FFFF) * DIM)[lane];
        unsigned int h1 = reinterpret_cast<const unsigned int*>(
            Hbf + (size_t)(k1 & 0x1FFFF) * DIM)[lane];
        unsigned int h2 = reinterpret_cast<const unsigned int*>(
            Hbf + (size_t)(k2 & 0x1FFFF) * DIM)[lane];
        unsigned int h3 = reinterpret_cast<const unsigned int*>(
            Hbf + (size_t)(k3 & 0x1FFFF) * DIM)[lane];

        int kk[4] = {k0, k1, k2, k3};
        float vv[4] = {v0, v1, v2, v3};
        unsigned int hh[4] = {h0, h1, h2, h3};
#pragma unroll
        for (int u = 0; u < 4; ++u) {
            float4 a = Af[((unsigned)kk[u] >> 17) & 7];
            float hx = bf_lo(hh[u]), hy = bf_hi(hh[u]);
            float s0 = vv[u] * a.x, s1 = vv[u] * a.y;
            float s2 = vv[u] * a.z, s3 = vv[u] * a.w;
            acc[0].x += s0 * hx; acc[0].y += s0 * hy;
            acc[1].x += s1 * hx; acc[1].y += s1 * hy;
            acc[2].x += s2 * hx; acc[2].y += s2 * hy;
            acc[3].x += s3 * hx; acc[3].y += s3 * hy;
        }
    }
    for (; i < e; ++i) {
        int2 m = sorted[i];
        int k = __builtin_amdgcn_readfirstlane(m.x);
        float v = __uint_as_float(__builtin_amdgcn_readfirstlane(m.y));
        unsigned int h = reinterpret_cast<const unsigned int*>(
            Hbf + (size_t)(k & 0x1FFFF) * DIM)[lane];
        float4 a = Af[((unsigned)k >> 17) & 7];
        float hx = bf_lo(h), hy = bf_hi(h);
        float s0 = v * a.x, s1 = v * a.y, s2 = v * a.z, s3 = v * a.w;
        acc[0].x += s0 * hx; acc[0].y += s0 * hy;
        acc[1].x += s1 * hx; acc[1].y += s1 * hy;
        acc[2].x += s2 * hx; acc[2].y += s2 * hy;
        acc[3].x += s3 * hx; acc[3].y += s3 * hy;
    }

    unsigned short* arow = Agg + (size_t)wid * 512 + lane * 2;
#pragma unroll
    for (int b = 0; b < 4; ++b) {
        unsigned int pk = (unsigned int)f2bf(acc[b].x)
                        | ((unsigned int)f2bf(acc[b].y) << 16);
        *reinterpret_cast<unsigned int*>(arow + b * 128) = pk;
    }
}

// ---------------------------------------------------------------------------
// K_B v2: out = Agg @ V  (M=Ne, K=512, N=128), MFMA, full-N per wave.
// Entire V fragment set (128 KB) lives in LDS (1 block/CU); 256 persistent
// blocks x 8 waves; each wave: 16-node tile, reads each Agg row exactly
// ONCE (16 x b128), 128 MFMAs, writes the full 512B output row itself
// (clean line merges -> no write amplification).
// ---------------------------------------------------------------------------
__global__ __launch_bounds__(512) void vgemm_kernel(
    const unsigned short* __restrict__ Agg,
    const unsigned short* __restrict__ VfragG,
    float* __restrict__ out, int Ne, int nTiles)
{
    __shared__ short8 ldsV[8192];   // full [b][ot][ks][lane], 128 KB
    int tid = threadIdx.x;
    for (int i = tid; i < 8192; i += 512)
        ldsV[i] = reinterpret_cast<const short8*>(VfragG)[i];
    __syncthreads();

    int wave = tid >> 6;
    int lane = tid & 63;
    int quad = lane >> 4, l15 = lane & 15;

    int wgid = blockIdx.x * 8 + wave;
    int nw   = gridDim.x * 8;

    for (int tile = wgid; tile < nTiles; tile += nw) {
        int node = tile * 16 + l15;
        int rdnode = node < Ne ? node : Ne - 1;

        // full-K B fragments: each Agg row read exactly once
        const short8* bp = reinterpret_cast<const short8*>(Agg)
                         + (size_t)rdnode * 64 + quad;
        short8 bf[16];
#pragma unroll
        for (int b = 0; b < 4; ++b)
#pragma unroll
            for (int ks = 0; ks < 4; ++ks)
                bf[b * 4 + ks] = bp[b * 16 + ks * 4];

        floatx4 acc[8];
#pragma unroll
        for (int o = 0; o < 8; ++o) acc[o] = (floatx4){0.f, 0.f, 0.f, 0.f};

#pragma unroll
        for (int b = 0; b < 4; ++b)
#pragma unroll
            for (int ks = 0; ks < 4; ++ks)
#pragma unroll
                for (int ot = 0; ot < 8; ++ot)
                    acc[ot] = __builtin_amdgcn_mfma_f32_16x16x32_bf16(
                        ldsV[((b * 8 + ot) * 4 + ks) * 64 + lane],
                        bf[b * 4 + ks], acc[ot], 0, 0, 0);

        if (node < Ne) {
            float* orow = out + (size_t)node * DIM + quad * 4;
#pragma unroll
            for (int ot = 0; ot < 8; ++ot) {
                float4 st;
                st.x = acc[ot][0]; st.y = acc[ot][1];
                st.z = acc[ot][2]; st.w = acc[ot][3];
                *reinterpret_cast<float4*>(orow + ot * 16) = st;
            }
        }
    }
}

// ---------------------------------------------------------------------------
// Fallback (ws too small): round-2 atomic kernel
// ---------------------------------------------------------------------------
__global__ __launch_bounds__(256) void rgcn_main(
    const unsigned short* __restrict__ Hbf,
    const unsigned short* __restrict__ Wfrag,
    const int*   __restrict__ erow,
    const int*   __restrict__ ecol,
    const float* __restrict__ eval,
    float*       __restrict__ out,
    int E, int groups_per_rel, int waves_per_rel)
{
    int wid  = blockIdx.x * 4 + (threadIdx.x >> 6);
    int lane = threadIdx.x & 63;
    int r    = wid & 7;
    int wr   = wid >> 3;
    int quad = lane >> 4;
    int l15  = lane & 15;

    short8 b[8][4];
    {
        const short8* wp = reinterpret_cast<const short8*>(
            Wfrag + (size_t)r * 16384);
#pragma unroll
        for (int ot = 0; ot < 8; ++ot)
#pragma unroll
            for (int ks = 0; ks < 4; ++ks)
                b[ot][ks] = wp[(ot * 4 + ks) * 64 + lane];
    }

    for (int g = wr; g < groups_per_rel; g += waves_per_rel) {
        int ebase = r * E + g * 16;
        int   colv = ecol[ebase + l15];
        int   rowv = erow[ebase + l15];
        float valv = eval[ebase + l15];

        short8 a[4];
        const unsigned short* hp = Hbf + (size_t)colv * DIM + quad * 8;
#pragma unroll
        for (int ks = 0; ks < 4; ++ks)
            a[ks] = *reinterpret_cast<const short8*>(hp + ks * 32);

        floatx4 acc[8];
#pragma unroll
        for (int ot = 0; ot < 8; ++ot) acc[ot] = (floatx4){0.f, 0.f, 0.f, 0.f};
#pragma unroll
        for (int ot = 0; ot < 8; ++ot)
#pragma unroll
            for (int ks = 0; ks < 4; ++ks)
                acc[ot] = __builtin_amdgcn_mfma_f32_16x16x32_bf16(
                    a[ks], b[ot][ks], acc[ot], 0, 0, 0);

        int   row4[4];
        float val4[4];
#pragma unroll
        for (int reg = 0; reg < 4; ++reg) {
            int src  = quad * 4 + reg;
            row4[reg] = __shfl(rowv, src, 64);
            val4[reg] = __shfl(valv, src, 64);
        }
#pragma unroll
        for (int ot = 0; ot < 8; ++ot)
#pragma unroll
            for (int reg = 0; reg < 4; ++reg) {
                float m = acc[ot][reg] * val4[reg];
                atomicAdd(out + (size_t)row4[reg] * DIM + ot * 16 + l15, m);
            }
    }
}

extern "C" void kernel_launch(void* const* d_in, const int* in_sizes, int n_in,
                              void* d_out, int out_size, void* d_ws, size_t ws_size,
                              hipStream_t stream)
{
    const float* H    = (const float*)d_in[0];
    const float* A    = (const float*)d_in[1];
    const float* V    = (const float*)d_in[2];
    const int*   erow = (const int*)d_in[3];
    const int*   ecol = (const int*)d_in[4];
    const float* eval = (const float*)d_in[5];
    float* out = (float*)d_out;

    int Ne    = in_sizes[0] / DIM;   // 100000
    int NEtot = in_sizes[3];         // 1.6M
    int E     = NEtot / NR;          // 200000

    auto al = [](size_t x) { return (x + 255) & ~(size_t)255; };

    int nbuc = (Ne + BROWS - 1) / BROWS;   // 196

    size_t offHbf    = 0;
    size_t offVfrag  = offHbf    + al((size_t)Ne * DIM * 2);
    size_t offWfrag  = offVfrag  + al((size_t)8192 * 16);
    size_t offAgg    = offWfrag  + al((size_t)16384 * 16);  // sorted1 aliases here
    size_t offRow    = offAgg    + al((size_t)Ne * 512 * 2);
    size_t offBcnt   = offRow    + al(((size_t)Ne + 2) * 4);
    size_t offBstart = offBcnt   + al((size_t)256 * 4);
    size_t offSort   = offBstart + al((size_t)256 * 4);
    size_t total     = offSort   + al((size_t)NEtot * 8);
    // sorted1 (196*16384*8 = 25.7 MB) aliases the Agg region (102.4 MB): it is
    // dead before agg_kernel writes Agg.

    char* ws = (char*)d_ws;
    unsigned short* Hbf    = (unsigned short*)(ws + offHbf);
    unsigned short* VfragG = (unsigned short*)(ws + offVfrag);
    unsigned short* Wfrag  = (unsigned short*)(ws + offWfrag);

    int n8 = Ne * DIM / 8;
    h_to_bf<<<(n8 + 255) / 256, 256, 0, stream>>>(H, Hbf, n8);

    if (ws_size < total) {
        // fallback: atomic-scatter path (round 2)
        build_wfrag<<<64, 256, 0, stream>>>(A, V, Wfrag);
        hipMemsetAsync(d_out, 0, (size_t)Ne * DIM * sizeof(float), stream);
        int blocks = 4096;
        int waves_per_rel = blocks * 4 / NR;
        int groups_per_rel = E / 16;
        rgcn_main<<<blocks, 256, 0, stream>>>(Hbf, Wfrag, erow, ecol, eval, out,
                                              E, groups_per_rel, waves_per_rel);
        return;
    }

    unsigned short* Agg      = (unsigned short*)(ws + offAgg);
    int2*           sorted1  = (int2*)(ws + offAgg);   // alias (dead before Agg)
    int*            rowStart = (int*)(ws + offRow);
    int*            bcnt     = (int*)(ws + offBcnt);
    int*            bstart   = (int*)(ws + offBstart);
    int2*           sorted   = (int2*)(ws + offSort);

    build_vfrag<<<32, 256, 0, stream>>>(V, VfragG);

    // two-level bucket sort (no global histogram / scan prologue)
    hipMemsetAsync(bcnt, 0, 256 * 4, stream);
    int sblocks = 512;
    int chunk   = (NEtot + sblocks - 1) / sblocks;   // 3125
    bucket_scatter<<<sblocks, 256, 0, stream>>>(erow, ecol, eval, bcnt,
                                                sorted1, NEtot, E, chunk);
    bucket_scan<<<1, 256, 0, stream>>>(bcnt, bstart, rowStart, nbuc, Ne);
    bucket_sort<<<nbuc, 256, 0, stream>>>(sorted1, bcnt, bstart, rowStart,
                                          sorted, Ne);

    // K_A: 4-basis aggregation (scalarized control path, no atomics)
    agg_kernel<<<(Ne + 3) / 4, 256, 0, stream>>>(Hbf, rowStart, sorted, A,
                                                 Agg, Ne);

    // K_B v2: out = Agg @ V via MFMA, full V in 128KB LDS, persistent blocks
    int nTiles = (Ne + 15) / 16;   // 6250
    vgemm_kernel<<<256, 512, 0, stream>>>(Agg, VfragG, out, Ne, nTiles);
}

// Round 8
// 377.783 us; speedup vs baseline: 1.2828x; 1.2828x over previous
//
#include <hip/hip_runtime.h>

typedef __attribute__((ext_vector_type(8))) short short8;
typedef __attribute__((ext_vector_type(4))) float floatx4;

constexpr int DIM   = 128;   // dim_in == dim_out
constexpr int NB    = 4;     // bases
constexpr int NR    = 8;     // relations
constexpr int BROWS = 512;   // rows per sort bucket
constexpr int BCAP  = 16384; // fixed bucket capacity (mean 8192, +90 sigma)

static __device__ __forceinline__ unsigned short f2bf(float f) {
    unsigned int u = __float_as_uint(f);
    u += 0x7FFFu + ((u >> 16) & 1u);
    return (unsigned short)(u >> 16);
}
static __device__ __forceinline__ float bf_lo(unsigned int h) {
    return __uint_as_float(h << 16);
}
static __device__ __forceinline__ float bf_hi(unsigned int h) {
    return __uint_as_float(h & 0xFFFF0000u);
}

// ---------------------------------------------------------------------------
// Vfrag[b][ot][ks][lane][j] = V[b][k][o], k=ks*32+(lane>>4)*8+j, o=ot*16+(lane&15)
// ---------------------------------------------------------------------------
__global__ __launch_bounds__(256) void build_vfrag(
    const float* __restrict__ V, unsigned short* __restrict__ VfragG)
{
    int idx  = blockIdx.x * 256 + threadIdx.x;   // 0 .. 8191
    int lane = idx & 63;
    int ks   = (idx >> 6) & 3;
    int ot   = (idx >> 8) & 7;
    int b    = idx >> 11;

    int o  = ot * 16 + (lane & 15);
    int kb = ks * 32 + (lane >> 4) * 8;

    short8 v;
#pragma unroll
    for (int j = 0; j < 8; ++j)
        v[j] = (short)f2bf(V[((size_t)b * DIM + kb + j) * DIM + o]);
    *reinterpret_cast<short8*>(VfragG + (size_t)idx * 8) = v;
}

// ---------------------------------------------------------------------------
// W_r fragments (fallback path only)
// ---------------------------------------------------------------------------
__global__ __launch_bounds__(256) void build_wfrag(
    const float* __restrict__ A, const float* __restrict__ V,
    unsigned short* __restrict__ Wfrag)
{
    int idx  = blockIdx.x * 256 + threadIdx.x;   // 0 .. 16383
    int lane = idx & 63;
    int ks   = (idx >> 6) & 3;
    int ot   = (idx >> 8) & 7;
    int r    = idx >> 11;

    int o     = ot * 16 + (lane & 15);
    int kbase = ks * 32 + (lane >> 4) * 8;

    float a0 = A[r * NB + 0], a1 = A[r * NB + 1];
    float a2 = A[r * NB + 2], a3 = A[r * NB + 3];

    short8 v;
#pragma unroll
    for (int j = 0; j < 8; ++j) {
        int k = kbase + j;
        float w = a0 * V[(0 * DIM + k) * DIM + o]
                + a1 * V[(1 * DIM + k) * DIM + o]
                + a2 * V[(2 * DIM + k) * DIM + o]
                + a3 * V[(3 * DIM + k) * DIM + o];
        v[j] = (short)f2bf(w);
    }
    *reinterpret_cast<short8*>(Wfrag + (size_t)idx * 8) = v;
}

// ---------------------------------------------------------------------------
// H (fp32) -> Hbf (bf16), row-major [Ne][128]. Streamed: nt loads + nt stores.
// ---------------------------------------------------------------------------
__global__ __launch_bounds__(256) void h_to_bf(
    const float* __restrict__ H, unsigned short* __restrict__ Hbf, int n8)
{
    int i = blockIdx.x * 256 + threadIdx.x;
    if (i >= n8) return;
    const floatx4* hp = reinterpret_cast<const floatx4*>(H) + (size_t)i * 2;
    floatx4 f0 = __builtin_nontemporal_load(hp);
    floatx4 f1 = __builtin_nontemporal_load(hp + 1);
    short8 v;
    v[0] = (short)f2bf(f0[0]); v[1] = (short)f2bf(f0[1]);
    v[2] = (short)f2bf(f0[2]); v[3] = (short)f2bf(f0[3]);
    v[4] = (short)f2bf(f1[0]); v[5] = (short)f2bf(f1[1]);
    v[6] = (short)f2bf(f1[2]); v[7] = (short)f2bf(f1[3]);
    __builtin_nontemporal_store(v, reinterpret_cast<short8*>(Hbf + (size_t)i * 8));
}

// ---------------------------------------------------------------------------
// Sort pass 1: scatter edges into fixed-capacity coarse buckets
// (bucket = row >> 9). Per-block LDS histogram -> one global atomicAdd per
// (block,bucket) -> contiguous runs. Record stores are nontemporal.
// Record: key = localRow<<20 | r<<17 | col  (9 | 3 | 17 bits), val fp32.
// ---------------------------------------------------------------------------
__global__ __launch_bounds__(256) void bucket_scatter(
    const int* __restrict__ erow, const int* __restrict__ ecol,
    const float* __restrict__ eval, int* __restrict__ bcnt,
    long long* __restrict__ sorted1, int n, int E, int chunk)
{
    __shared__ int cnt[256];
    __shared__ int base[256];
    int t = threadIdx.x;
    cnt[t] = 0;
    __syncthreads();

    int s = blockIdx.x * chunk;
    int e = s + chunk; if (e > n) e = n;

    for (int i = s + t; i < e; i += 256)
        atomicAdd(&cnt[erow[i] >> 9], 1);
    __syncthreads();

    int c = cnt[t];
    base[t] = (c > 0) ? atomicAdd(&bcnt[t], c) : 0;
    cnt[t] = 0;
    __syncthreads();

    for (int i = s + t; i < e; i += 256) {
        int row = erow[i];
        int bkt = row >> 9;
        int rank = atomicAdd(&cnt[bkt], 1);
        int r = (int)((unsigned)i / (unsigned)E);
        int col = __builtin_nontemporal_load(ecol + i);
        float v = __builtin_nontemporal_load(eval + i);
        unsigned int key = ((unsigned)(row & (BROWS - 1)) << 20)
                         | ((unsigned)r << 17) | (unsigned)col;
        long long rec = ((long long)__float_as_int(v) << 32) | (long long)key;
        __builtin_nontemporal_store(rec,
            sorted1 + (size_t)bkt * BCAP + base[bkt] + rank);
    }
}

// ---------------------------------------------------------------------------
// Exclusive scan over the 196 bucket counts (single block); also finalize
// rowStart[Ne] = total edge count.
// ---------------------------------------------------------------------------
__global__ __launch_bounds__(256) void bucket_scan(
    const int* __restrict__ bcnt, int* __restrict__ bstart,
    int* __restrict__ rowStart, int nbuc, int Ne)
{
    __shared__ int sd[256];
    int t = threadIdx.x;
    int c = (t < nbuc) ? bcnt[t] : 0;
    sd[t] = c; __syncthreads();
#pragma unroll
    for (int off = 1; off < 256; off <<= 1) {
        int v = (t >= off) ? sd[t - off] : 0;
        __syncthreads();
        sd[t] += v;
        __syncthreads();
    }
    if (t < nbuc) bstart[t] = sd[t] - c;
    if (t == nbuc - 1) rowStart[Ne] = sd[t];
}

// ---------------------------------------------------------------------------
// Sort pass 2: one block per bucket. Contiguous read of the bucket's
// records; per-row LDS histogram + scan -> emits rowStart for its 512 rows
// and compacts records to exact final positions (writes land in the
// bucket's ~128KB output window -> L2-absorbed).
// ---------------------------------------------------------------------------
__global__ __launch_bounds__(256) void bucket_sort(
    const int2* __restrict__ sorted1, const int* __restrict__ bcnt,
    const int* __restrict__ bstart, int* __restrict__ rowStart,
    int2* __restrict__ sorted, int Ne)
{
    __shared__ int hcnt[BROWS];
    __shared__ int hoff[BROWS];
    int b = blockIdx.x;
    int t = threadIdx.x;
    hcnt[t] = 0; hcnt[t + 256] = 0;
    __syncthreads();

    int n = bcnt[b];
    const int2* src = sorted1 + (size_t)b * BCAP;

    for (int i = t; i < n; i += 256)
        atomicAdd(&hcnt[(unsigned)src[i].x >> 20], 1);
    __syncthreads();

    if (t == 0) {
        int run = 0;
#pragma unroll 8
        for (int j = 0; j < BROWS; ++j) { hoff[j] = run; run += hcnt[j]; }
    }
    __syncthreads();

    int bs = bstart[b];
    int rs = b * BROWS;
    int nr = Ne - rs; if (nr > BROWS) nr = BROWS;
    for (int j = t; j < nr; j += 256)
        rowStart[rs + j] = bs + hoff[j];

    hcnt[t] = 0; hcnt[t + 256] = 0;
    __syncthreads();

    for (int i = t; i < n; i += 256) {
        int2 m = src[i];
        int lr = (unsigned)m.x >> 20;
        int pos = bs + hoff[lr] + atomicAdd(&hcnt[lr], 1);
        sorted[pos] = m;
    }
}

// ---------------------------------------------------------------------------
// K_A: basis aggregation. One wave per destination row.
// Agg[row][b*128 + i] = sum_{edges->row} val*A[r,b]*Hbf[col][i]   (bf16 out)
// Control path scalarized via readfirstlane; Agg stores are NONTEMPORAL so
// the 102 MB write stream does not evict the L3-resident Hbf gather set.
// ---------------------------------------------------------------------------
__global__ __launch_bounds__(256) void agg_kernel(
    const unsigned short* __restrict__ Hbf,
    const int*  __restrict__ rowStart,
    const int2* __restrict__ sorted,
    const float* __restrict__ Aw,
    unsigned short* __restrict__ Agg, int Ne)
{
    int tid  = threadIdx.x;
    int wid  = __builtin_amdgcn_readfirstlane(blockIdx.x * 4 + (tid >> 6));
    if (wid >= Ne) return;
    int lane = tid & 63;

    int s = __builtin_amdgcn_readfirstlane(rowStart[wid]);
    int e = __builtin_amdgcn_readfirstlane(rowStart[wid + 1]);

    const float4* Af = reinterpret_cast<const float4*>(Aw);

    float2 acc[4];
#pragma unroll
    for (int b = 0; b < 4; ++b) { acc[b].x = 0.f; acc[b].y = 0.f; }

    int i = s;
    for (; i + 4 <= e; i += 4) {
        int2 m0 = sorted[i],     m1 = sorted[i + 1];
        int2 m2 = sorted[i + 2], m3 = sorted[i + 3];
        int k0 = __builtin_amdgcn_readfirstlane(m0.x);
        int k1 = __builtin_amdgcn_readfirstlane(m1.x);
        int k2 = __builtin_amdgcn_readfirstlane(m2.x);
        int k3 = __builtin_amdgcn_readfirstlane(m3.x);
        float v0 = __uint_as_float(__builtin_amdgcn_readfirstlane(m0.y));
        float v1 = __uint_as_float(__builtin_amdgcn_readfirstlane(m1.y));
        float v2 = __uint_as_float(__builtin_amdgcn_readfirstlane(m2.y));
        float v3 = __uint_as_float(__builtin_amdgcn_readfirstlane(m3.y));

        unsigned int h0 = reinterpret_cast<const unsigned int*>(
            Hbf + (size_t)(k0 & 0x1FFFF) * DIM)[lane];
        unsigned int h1 = reinterpret_cast<const unsigned int*>(
            Hbf + (size_t)(k1 & 0x1FFFF) * DIM)[lane];
        unsigned int h2 = reinterpret_cast<const unsigned int*>(
            Hbf + (size_t)(k2 & 0x1FFFF) * DIM)[lane];
        unsigned int h3 = reinterpret_cast<const unsigned int*>(
            Hbf + (size_t)(k3 & 0x1FFFF) * DIM)[lane];

        int kk[4] = {k0, k1, k2, k3};
        float vv[4] = {v0, v1, v2, v3};
        unsigned int hh[4] = {h0, h1, h2, h3};
#pragma unroll
        for (int u = 0; u < 4; ++u) {
            float4 a = Af[((unsigned)kk[u] >> 17) & 7];
            float hx = bf_lo(hh[u]), hy = bf_hi(hh[u]);
            float s0 = vv[u] * a.x, s1 = vv[u] * a.y;
            float s2 = vv[u] * a.z, s3 = vv[u] * a.w;
            acc[0].x += s0 * hx; acc[0].y += s0 * hy;
            acc[1].x += s1 * hx; acc[1].y += s1 * hy;
            acc[2].x += s2 * hx; acc[2].y += s2 * hy;
            acc[3].x += s3 * hx; acc[3].y += s3 * hy;
        }
    }
    for (; i < e; ++i) {
        int2 m = sorted[i];
        int k = __builtin_amdgcn_readfirstlane(m.x);
        float v = __uint_as_float(__builtin_amdgcn_readfirstlane(m.y));
        unsigned int h = reinterpret_cast<const unsigned int*>(
            Hbf + (size_t)(k & 0x1FFFF) * DIM)[lane];
        float4 a = Af[((unsigned)k >> 17) & 7];
        float hx = bf_lo(h), hy = bf_hi(h);
        float s0 = v * a.x, s1 = v * a.y, s2 = v * a.z, s3 = v * a.w;
        acc[0].x += s0 * hx; acc[0].y += s0 * hy;
        acc[1].x += s1 * hx; acc[1].y += s1 * hy;
        acc[2].x += s2 * hx; acc[2].y += s2 * hy;
        acc[3].x += s3 * hx; acc[3].y += s3 * hy;
    }

    unsigned short* arow = Agg + (size_t)wid * 512 + lane * 2;
#pragma unroll
    for (int b = 0; b < 4; ++b) {
        unsigned int pk = (unsigned int)f2bf(acc[b].x)
                        | ((unsigned int)f2bf(acc[b].y) << 16);
        __builtin_nontemporal_store(pk,
            reinterpret_cast<unsigned int*>(arow + b * 128));
    }
}

// ---------------------------------------------------------------------------
// K_B: out = Agg @ V  (M=Ne, K=512, N=128), MFMA. Round-6 structure
// (64 KB LDS = one 64-col half of V; N split across block pairs).
// out stores are nontemporal (never re-read).
// ---------------------------------------------------------------------------
__global__ __launch_bounds__(512) void vgemm_kernel(
    const unsigned short* __restrict__ Agg,
    const unsigned short* __restrict__ VfragG,
    float* __restrict__ out, int Ne, int nTiles)
{
    __shared__ short8 ldsV[4096];   // [b][otl][ks][lane], 64 KB
    int half = blockIdx.x & 1;
    int blk  = blockIdx.x >> 1;
    int nblk = gridDim.x >> 1;
    int tid  = threadIdx.x;

    for (int i = tid; i < 4096; i += 512) {
        int lane = i & 63, ks = (i >> 6) & 3, otl = (i >> 8) & 3, b = i >> 10;
        int gi = ((b * 8 + half * 4 + otl) * 4 + ks) * 64 + lane;
        ldsV[i] = reinterpret_cast<const short8*>(VfragG)[gi];
    }
    __syncthreads();

    int wave = tid >> 6;
    int lane = tid & 63;
    int quad = lane >> 4, l15 = lane & 15;

    int wgid = blk * 8 + wave;
    int nw   = nblk * 8;

    for (int tile = wgid; tile < nTiles; tile += nw) {
        int node0 = tile * 16;
        int node  = node0 + l15;
        int rdnode = node < Ne ? node : Ne - 1;

        const short8* bp = reinterpret_cast<const short8*>(Agg)
                         + (size_t)rdnode * 64 + quad;
        short8 bf[16];
#pragma unroll
        for (int b = 0; b < 4; ++b)
#pragma unroll
            for (int ks = 0; ks < 4; ++ks)
                bf[b * 4 + ks] = bp[b * 16 + ks * 4];

        floatx4 acc[4];
#pragma unroll
        for (int o = 0; o < 4; ++o) acc[o] = (floatx4){0.f, 0.f, 0.f, 0.f};

#pragma unroll
        for (int b = 0; b < 4; ++b)
#pragma unroll
            for (int ks = 0; ks < 4; ++ks)
#pragma unroll
                for (int otl = 0; otl < 4; ++otl)
                    acc[otl] = __builtin_amdgcn_mfma_f32_16x16x32_bf16(
                        ldsV[((b * 4 + otl) * 4 + ks) * 64 + lane],
                        bf[b * 4 + ks], acc[otl], 0, 0, 0);

        if (node < Ne) {
            float* orow = out + (size_t)node * DIM + half * 64;
#pragma unroll
            for (int otl = 0; otl < 4; ++otl) {
                __builtin_nontemporal_store(acc[otl],
                    reinterpret_cast<floatx4*>(orow + otl * 16 + quad * 4));
            }
        }
    }
}

// ---------------------------------------------------------------------------
// Fallback (ws too small): round-2 atomic kernel
// ---------------------------------------------------------------------------
__global__ __launch_bounds__(256) void rgcn_main(
    const unsigned short* __restrict__ Hbf,
    const unsigned short* __restrict__ Wfrag,
    const int*   __restrict__ erow,
    const int*   __restrict__ ecol,
    const float* __restrict__ eval,
    float*       __restrict__ out,
    int E, int groups_per_rel, int waves_per_rel)
{
    int wid  = blockIdx.x * 4 + (threadIdx.x >> 6);
    int lane = threadIdx.x & 63;
    int r    = wid & 7;
    int wr   = wid >> 3;
    int quad = lane >> 4;
    int l15  = lane & 15;

    short8 b[8][4];
    {
        const short8* wp = reinterpret_cast<const short8*>(
            Wfrag + (size_t)r * 16384);
#pragma unroll
        for (int ot = 0; ot < 8; ++ot)
#pragma unroll
            for (int ks = 0; ks < 4; ++ks)
                b[ot][ks] = wp[(ot * 4 + ks) * 64 + lane];
    }

    for (int g = wr; g < groups_per_rel; g += waves_per_rel) {
        int ebase = r * E + g * 16;
        int   colv = ecol[ebase + l15];
        int   rowv = erow[ebase + l15];
        float valv = eval[ebase + l15];

        short8 a[4];
        const unsigned short* hp = Hbf + (size_t)colv * DIM + quad * 8;
#pragma unroll
        for (int ks = 0; ks < 4; ++ks)
            a[ks] = *reinterpret_cast<const short8*>(hp + ks * 32);

        floatx4 acc[8];
#pragma unroll
        for (int ot = 0; ot < 8; ++ot) acc[ot] = (floatx4){0.f, 0.f, 0.f, 0.f};
#pragma unroll
        for (int ot = 0; ot < 8; ++ot)
#pragma unroll
            for (int ks = 0; ks < 4; ++ks)
                acc[ot] = __builtin_amdgcn_mfma_f32_16x16x32_bf16(
                    a[ks], b[ot][ks], acc[ot], 0, 0, 0);

        int   row4[4];
        float val4[4];
#pragma unroll
        for (int reg = 0; reg < 4; ++reg) {
            int src  = quad * 4 + reg;
            row4[reg] = __shfl(rowv, src, 64);
            val4[reg] = __shfl(valv, src, 64);
        }
#pragma unroll
        for (int ot = 0; ot < 8; ++ot)
#pragma unroll
            for (int reg = 0; reg < 4; ++reg) {
                float m = acc[ot][reg] * val4[reg];
                atomicAdd(out + (size_t)row4[reg] * DIM + ot * 16 + l15, m);
            }
    }
}

extern "C" void kernel_launch(void* const* d_in, const int* in_sizes, int n_in,
                              void* d_out, int out_size, void* d_ws, size_t ws_size,
                              hipStream_t stream)
{
    const float* H    = (const float*)d_in[0];
    const float* A    = (const float*)d_in[1];
    const float* V    = (const float*)d_in[2];
    const int*   erow = (const int*)d_in[3];
    const int*   ecol = (const int*)d_in[4];
    const float* eval = (const float*)d_in[5];
    float* out = (float*)d_out;

    int Ne    = in_sizes[0] / DIM;   // 100000
    int NEtot = in_sizes[3];         // 1.6M
    int E     = NEtot / NR;          // 200000

    auto al = [](size_t x) { return (x + 255) & ~(size_t)255; };

    int nbuc = (Ne + BROWS - 1) / BROWS;   // 196

    size_t offHbf    = 0;
    size_t offVfrag  = offHbf    + al((size_t)Ne * DIM * 2);
    size_t offWfrag  = offVfrag  + al((size_t)8192 * 16);
    size_t offAgg    = offWfrag  + al((size_t)16384 * 16);  // sorted1 aliases here
    size_t offRow    = offAgg    + al((size_t)Ne * 512 * 2);
    size_t offBcnt   = offRow    + al(((size_t)Ne + 2) * 4);
    size_t offBstart = offBcnt   + al((size_t)256 * 4);
    size_t offSort   = offBstart + al((size_t)256 * 4);
    size_t total     = offSort   + al((size_t)NEtot * 8);
    // sorted1 (196*16384*8 = 25.7 MB) aliases the Agg region (102.4 MB): it is
    // dead before agg_kernel writes Agg.

    char* ws = (char*)d_ws;
    unsigned short* Hbf    = (unsigned short*)(ws + offHbf);
    unsigned short* VfragG = (unsigned short*)(ws + offVfrag);
    unsigned short* Wfrag  = (unsigned short*)(ws + offWfrag);

    int n8 = Ne * DIM / 8;
    h_to_bf<<<(n8 + 255) / 256, 256, 0, stream>>>(H, Hbf, n8);

    if (ws_size < total) {
        // fallback: atomic-scatter path (round 2)
        build_wfrag<<<64, 256, 0, stream>>>(A, V, Wfrag);
        hipMemsetAsync(d_out, 0, (size_t)Ne * DIM * sizeof(float), stream);
        int blocks = 4096;
        int waves_per_rel = blocks * 4 / NR;
        int groups_per_rel = E / 16;
        rgcn_main<<<blocks, 256, 0, stream>>>(Hbf, Wfrag, erow, ecol, eval, out,
                                              E, groups_per_rel, waves_per_rel);
        return;
    }

    unsigned short* Agg      = (unsigned short*)(ws + offAgg);
    long long*      sorted1  = (long long*)(ws + offAgg); // alias (dead before Agg)
    int*            rowStart = (int*)(ws + offRow);
    int*            bcnt     = (int*)(ws + offBcnt);
    int*            bstart   = (int*)(ws + offBstart);
    int2*           sorted   = (int2*)(ws + offSort);

    build_vfrag<<<32, 256, 0, stream>>>(V, VfragG);

    // two-level bucket sort (no global histogram / scan prologue)
    hipMemsetAsync(bcnt, 0, 256 * 4, stream);
    int sblocks = 512;
    int chunk   = (NEtot + sblocks - 1) / sblocks;   // 3125
    bucket_scatter<<<sblocks, 256, 0, stream>>>(erow, ecol, eval, bcnt,
                                                sorted1, NEtot, E, chunk);
    bucket_scan<<<1, 256, 0, stream>>>(bcnt, bstart, rowStart, nbuc, Ne);
    bucket_sort<<<nbuc, 256, 0, stream>>>((const int2*)sorted1, bcnt, bstart,
                                          rowStart, sorted, Ne);

    // K_A: 4-basis aggregation (scalarized control, nt Agg stores)
    agg_kernel<<<(Ne + 3) / 4, 256, 0, stream>>>(Hbf, rowStart, sorted, A,
                                                 Agg, Ne);

    // K_B: out = Agg @ V via MFMA, V-frags in LDS (two 64-col halves)
    int nTiles = (Ne + 15) / 16;   // 6250
    vgemm_kernel<<<512, 512, 0, stream>>>(Agg, VfragG, out, Ne, nTiles);
}